// Round 2
// baseline (2254.775 us; speedup 1.0000x reference)
//
#include <hip/hip_runtime.h>
#include <hip/hip_fp16.h>
#include <stdint.h>

#define T_TOK 2048
#define HID   2880
#define INTERM 2880
#define N1    5760      // 2*INTERM, w1 inner dim
#define NEXP  8
#define TOPK  4

typedef _Float16 h4 __attribute__((ext_vector_type(4)));
typedef _Float16 h8 __attribute__((ext_vector_type(8)));
typedef float    f4 __attribute__((ext_vector_type(4)));

// ---------------- async global->LDS (16B per lane, wave-uniform LDS base) ----
__device__ __forceinline__ void gl_lds16(const void* g, void* l) {
  __builtin_amdgcn_global_load_lds(
      (const __attribute__((address_space(1))) unsigned int*)g,
      (__attribute__((address_space(3))) unsigned int*)l, 16, 0, 0);
}

// ---------------- router: logits -> top4 -> softmax -> cw + expert lists -----
__global__ __launch_bounds__(64) void k_router(
    const float* __restrict__ x, const float* __restrict__ gw,
    const float* __restrict__ gb, float* __restrict__ cw,
    int* __restrict__ list, int* __restrict__ cnt) {
  const int t = blockIdx.x;
  const int l = threadIdx.x;
  const float* xr = x + (size_t)t * HID;
  float acc[NEXP];
#pragma unroll
  for (int e = 0; e < NEXP; ++e) acc[e] = 0.f;
  for (int i = l; i < HID; i += 64) {
    float xv = xr[i];
    const float4* g = (const float4*)(gw + (size_t)i * NEXP);
    float4 g0 = g[0], g1 = g[1];
    acc[0] += xv * g0.x; acc[1] += xv * g0.y; acc[2] += xv * g0.z; acc[3] += xv * g0.w;
    acc[4] += xv * g1.x; acc[5] += xv * g1.y; acc[6] += xv * g1.z; acc[7] += xv * g1.w;
  }
#pragma unroll
  for (int off = 32; off >= 1; off >>= 1) {
#pragma unroll
    for (int e = 0; e < NEXP; ++e) acc[e] += __shfl_xor(acc[e], off);
  }
  if (l == 0) {
    float lg[NEXP];
#pragma unroll
    for (int e = 0; e < NEXP; ++e) lg[e] = acc[e] + gb[e];
    int idx[TOPK]; float val[TOPK]; unsigned used = 0;
#pragma unroll
    for (int k = 0; k < TOPK; ++k) {
      int best = 0; float bv = -1e30f;
#pragma unroll
      for (int e = 0; e < NEXP; ++e)
        if (!((used >> e) & 1) && lg[e] > bv) { bv = lg[e]; best = e; }
      used |= 1u << best; idx[k] = best; val[k] = bv;
    }
    float mx = val[0], s = 0.f, w[TOPK];
#pragma unroll
    for (int k = 0; k < TOPK; ++k) { w[k] = __expf(val[k] - mx); s += w[k]; }
    float inv = 1.f / s;
    float row[NEXP];
#pragma unroll
    for (int e = 0; e < NEXP; ++e) row[e] = 0.f;
#pragma unroll
    for (int k = 0; k < TOPK; ++k) row[idx[k]] = w[k] * inv;
#pragma unroll
    for (int e = 0; e < NEXP; ++e) cw[t * NEXP + e] = row[e];
#pragma unroll
    for (int k = 0; k < TOPK; ++k) {
      int p = atomicAdd(&cnt[idx[k]], 1);
      list[idx[k] * T_TOK + p] = t;
    }
  }
}

__global__ void k_scan(const int* __restrict__ cnt, int* __restrict__ offs) {
  if (threadIdx.x == 0) {
    int s = 0;
    for (int e = 0; e < NEXP; ++e) { offs[e] = s; s += cnt[e]; }
    offs[NEXP] = s;
  }
}

// ---------------- x fp32 -> fp16 ---------------------------------------------
__global__ __launch_bounds__(256) void k_cvt(const float* __restrict__ x,
                                             _Float16* __restrict__ xh) {
  int i = blockIdx.x * 256 + threadIdx.x;   // grid sized exactly: T*H/4 threads
  float4 v = ((const float4*)x)[i];
  h4 h = { (_Float16)v.x, (_Float16)v.y, (_Float16)v.z, (_Float16)v.w };
  ((h4*)xh)[i] = h;
}

// ---------------- GEMM1 + clamped SwiGLU -------------------------------------
// Block: 256 thr (4 waves). Tile: 128 rows x (64 glu + 64 lin cols) x BK=32.
// A (x fp16, gathered rows) via global_load_lds, pre-swizzled source.
// B (w1 fp32) reg-staged: 8 scalar loads/quad, cvt fp16, conflict-free b128
// LDS write (col=tid>>2, slot=tid&3 -> each wave writes contiguous 1024B).
__global__ __launch_bounds__(256) void k_gemm1(
    const _Float16* __restrict__ xh, const float* __restrict__ w1,
    const float* __restrict__ b1, const int* __restrict__ list,
    const int* __restrict__ cnt, const int* __restrict__ offs,
    _Float16* __restrict__ abuf) {
  const int e = blockIdx.z;
  const int c_e = cnt[e];
  const int m0 = blockIdx.y * 128;
  if (m0 >= c_e) return;
  const int n0 = blockIdx.x * 64;
  const int tid = threadIdx.x;
  const int wv = tid >> 6, l = tid & 63;

  __shared__ _Float16 As[128 * 32];
  __shared__ _Float16 Bs[2][64 * 32];

  const int* lst = list + e * T_TOK;
  const float* w1e = w1 + (size_t)e * HID * N1;
  const float* b1e = b1 + (size_t)e * N1;
  const int off_e = offs[e];

  // A staging: two gl_lds issues/wave; lane l -> row base+(l>>2), k-quad slot l&3
  const int rA0 = wv * 16 + (l >> 2);
  const int rA1 = rA0 + 64;
  const int t0 = lst[min(m0 + rA0, c_e - 1)];
  const int t1 = lst[min(m0 + rA1, c_e - 1)];
  const int q0 = (l & 3) ^ ((rA0 >> 1) & 3);   // pre-swizzled source k-quad
  const int q1 = (l & 3) ^ ((rA1 >> 1) & 3);
  const _Float16* srcA0 = xh + (size_t)t0 * HID + q0 * 8;
  const _Float16* srcA1 = xh + (size_t)t1 * HID + q1 * 8;
  _Float16* dstA0 = As + (wv * 16) * 32;        // wave-uniform LDS bases
  _Float16* dstA1 = As + (wv * 16 + 64) * 32;

  // B staging: thread owns one 16B quad: col cB = tid>>2, LDS slot sB = tid&3.
  // Per wave: 16 cols x 4 slots = contiguous 1024B -> conflict-free b128 write.
  const int cB = tid >> 2;
  const int sB = tid & 3;
  const int qB = sB ^ ((cB >> 1) & 3);          // source k-quad for this slot
  const int bwr = cB * 64 + sB * 16;            // byte offset in Bs[hh]
  const float* wB = w1e + (size_t)(qB * 8) * N1 + n0 + cB;

  f4 accg[2][4], accl[2][4];
#pragma unroll
  for (int m = 0; m < 2; ++m)
#pragma unroll
    for (int n = 0; n < 4; ++n) {
      accg[m][n] = (f4){0.f, 0.f, 0.f, 0.f};
      accl[m][n] = (f4){0.f, 0.f, 0.f, 0.f};
    }

  const int lr = l & 15, lg = l >> 4;
  int offA[2], offB[4];
#pragma unroll
  for (int m = 0; m < 2; ++m) {
    int r = wv * 32 + m * 16 + lr;
    offA[m] = r * 64 + ((lg ^ ((r >> 1) & 3)) * 16);
  }
#pragma unroll
  for (int n = 0; n < 4; ++n) {
    int nn = n * 16 + lr;
    offB[n] = nn * 64 + ((lg ^ ((nn >> 1) & 3)) * 16);
  }

  for (int kt = 0; kt < HID / 32; ++kt) {
    const int kb = kt * 32;
    gl_lds16(srcA0 + kb, dstA0);
    gl_lds16(srcA1 + kb, dstA1);
#pragma unroll
    for (int hh = 0; hh < 2; ++hh) {
      const float* wp = wB + (hh ? INTERM : 0);
      float v0 = wp[(size_t)(kb + 0) * N1];
      float v1 = wp[(size_t)(kb + 1) * N1];
      float v2 = wp[(size_t)(kb + 2) * N1];
      float v3 = wp[(size_t)(kb + 3) * N1];
      float v4 = wp[(size_t)(kb + 4) * N1];
      float v5 = wp[(size_t)(kb + 5) * N1];
      float v6 = wp[(size_t)(kb + 6) * N1];
      float v7 = wp[(size_t)(kb + 7) * N1];
      h8 pk = { (_Float16)v0, (_Float16)v1, (_Float16)v2, (_Float16)v3,
                (_Float16)v4, (_Float16)v5, (_Float16)v6, (_Float16)v7 };
      *(h8*)((char*)(&Bs[hh][0]) + bwr) = pk;
    }
    __syncthreads();
    h8 af0 = *(const h8*)((const char*)As + offA[0]);
    h8 af1 = *(const h8*)((const char*)As + offA[1]);
    h8 bg[4], bl[4];
#pragma unroll
    for (int n = 0; n < 4; ++n) {
      bg[n] = *(const h8*)((const char*)(&Bs[0][0]) + offB[n]);
      bl[n] = *(const h8*)((const char*)(&Bs[1][0]) + offB[n]);
    }
#pragma unroll
    for (int n = 0; n < 4; ++n) {
      accg[0][n] = __builtin_amdgcn_mfma_f32_16x16x32_f16(af0, bg[n], accg[0][n], 0, 0, 0);
      accg[1][n] = __builtin_amdgcn_mfma_f32_16x16x32_f16(af1, bg[n], accg[1][n], 0, 0, 0);
      accl[0][n] = __builtin_amdgcn_mfma_f32_16x16x32_f16(af0, bl[n], accl[0][n], 0, 0, 0);
      accl[1][n] = __builtin_amdgcn_mfma_f32_16x16x32_f16(af1, bl[n], accl[1][n], 0, 0, 0);
    }
    __syncthreads();
  }

  // epilogue: h -> clamped swiglu -> abuf (fp16)
  float bgv[4], blv[4];
#pragma unroll
  for (int n = 0; n < 4; ++n) {
    int c = n0 + n * 16 + lr;
    bgv[n] = b1e[c];
    blv[n] = b1e[INTERM + c];
  }
#pragma unroll
  for (int m = 0; m < 2; ++m) {
#pragma unroll
    for (int j = 0; j < 4; ++j) {
      int row_l = wv * 32 + m * 16 + lg * 4 + j;
      int grow = m0 + row_l;
      if (grow < c_e) {
        _Float16* arow = abuf + (size_t)(off_e + grow) * INTERM + n0 + lr;
#pragma unroll
        for (int n = 0; n < 4; ++n) {
          float hg = accg[m][n][j] + bgv[n];
          float hl = accl[m][n][j] + blv[n];
          hg = fminf(hg, 7.f);
          hl = fminf(fmaxf(hl, -7.f), 7.f);
          float sg = 1.f / (1.f + __expf(-1.702f * hg));
          arow[n * 16] = (_Float16)(hg * sg * (hl + 1.f));
        }
      }
    }
  }
}

// ---------------- GEMM2 + weighted scatter -----------------------------------
__global__ __launch_bounds__(256) void k_gemm2(
    const _Float16* __restrict__ abuf, const float* __restrict__ w2,
    const float* __restrict__ b2, const int* __restrict__ list,
    const int* __restrict__ cnt, const int* __restrict__ offs,
    const float* __restrict__ cw, float* __restrict__ out) {
  const int e = blockIdx.z;
  const int c_e = cnt[e];
  const int m0 = blockIdx.y * 128;
  if (m0 >= c_e) return;
  const int n0 = blockIdx.x * 64;
  const int tid = threadIdx.x;
  const int wv = tid >> 6, l = tid & 63;

  __shared__ _Float16 As[128 * 32];
  __shared__ _Float16 Bs[64 * 32];

  const int* lst = list + e * T_TOK;
  const float* w2e = w2 + (size_t)e * INTERM * HID;
  const float* b2e = b2 + (size_t)e * HID;
  const int off_e = offs[e];

  const int rA0 = wv * 16 + (l >> 2);
  const int rA1 = rA0 + 64;
  const int q0 = (l & 3) ^ ((rA0 >> 1) & 3);
  const int q1 = (l & 3) ^ ((rA1 >> 1) & 3);
  const _Float16* srcA0 = abuf + (size_t)(off_e + min(m0 + rA0, c_e - 1)) * INTERM + q0 * 8;
  const _Float16* srcA1 = abuf + (size_t)(off_e + min(m0 + rA1, c_e - 1)) * INTERM + q1 * 8;
  _Float16* dstA0 = As + (wv * 16) * 32;
  _Float16* dstA1 = As + (wv * 16 + 64) * 32;

  const int cB = tid >> 2;
  const int sB = tid & 3;
  const int qB = sB ^ ((cB >> 1) & 3);
  const int bwr = cB * 64 + sB * 16;
  const float* wB = w2e + (size_t)(qB * 8) * HID + n0 + cB;

  f4 acc[2][4];
#pragma unroll
  for (int m = 0; m < 2; ++m)
#pragma unroll
    for (int n = 0; n < 4; ++n) acc[m][n] = (f4){0.f, 0.f, 0.f, 0.f};

  const int lr = l & 15, lg = l >> 4;
  int offA[2], offB[4];
#pragma unroll
  for (int m = 0; m < 2; ++m) {
    int r = wv * 32 + m * 16 + lr;
    offA[m] = r * 64 + ((lg ^ ((r >> 1) & 3)) * 16);
  }
#pragma unroll
  for (int n = 0; n < 4; ++n) {
    int nn = n * 16 + lr;
    offB[n] = nn * 64 + ((lg ^ ((nn >> 1) & 3)) * 16);
  }

  for (int kt = 0; kt < INTERM / 32; ++kt) {
    const int kb = kt * 32;
    gl_lds16(srcA0 + kb, dstA0);
    gl_lds16(srcA1 + kb, dstA1);
    {
      float v0 = wB[(size_t)(kb + 0) * HID];
      float v1 = wB[(size_t)(kb + 1) * HID];
      float v2 = wB[(size_t)(kb + 2) * HID];
      float v3 = wB[(size_t)(kb + 3) * HID];
      float v4 = wB[(size_t)(kb + 4) * HID];
      float v5 = wB[(size_t)(kb + 5) * HID];
      float v6 = wB[(size_t)(kb + 6) * HID];
      float v7 = wB[(size_t)(kb + 7) * HID];
      h8 pk = { (_Float16)v0, (_Float16)v1, (_Float16)v2, (_Float16)v3,
                (_Float16)v4, (_Float16)v5, (_Float16)v6, (_Float16)v7 };
      *(h8*)((char*)Bs + bwr) = pk;
    }
    __syncthreads();
    h8 af0 = *(const h8*)((const char*)As + offA[0]);
    h8 af1 = *(const h8*)((const char*)As + offA[1]);
    h8 bf[4];
#pragma unroll
    for (int n = 0; n < 4; ++n) bf[n] = *(const h8*)((const char*)Bs + offB[n]);
#pragma unroll
    for (int n = 0; n < 4; ++n) {
      acc[0][n] = __builtin_amdgcn_mfma_f32_16x16x32_f16(af0, bf[n], acc[0][n], 0, 0, 0);
      acc[1][n] = __builtin_amdgcn_mfma_f32_16x16x32_f16(af1, bf[n], acc[1][n], 0, 0, 0);
    }
    __syncthreads();
  }

  float b2v[4];
#pragma unroll
  for (int n = 0; n < 4; ++n) b2v[n] = b2e[n0 + n * 16 + lr];
#pragma unroll
  for (int m = 0; m < 2; ++m) {
#pragma unroll
    for (int j = 0; j < 4; ++j) {
      int row_l = wv * 32 + m * 16 + lg * 4 + j;
      int grow = m0 + row_l;
      if (grow < c_e) {
        int t = lst[grow];
        float wgt = cw[t * NEXP + e];
        float* orow = out + (size_t)t * HID + n0 + lr;
#pragma unroll
        for (int n = 0; n < 4; ++n)
          atomicAdd(&orow[n * 16], wgt * (acc[m][n][j] + b2v[n]));
      }
    }
  }
}

// ---------------- launch -----------------------------------------------------
extern "C" void kernel_launch(void* const* d_in, const int* in_sizes, int n_in,
                              void* d_out, int out_size, void* d_ws, size_t ws_size,
                              hipStream_t stream) {
  const float* x  = (const float*)d_in[0];
  const float* gw = (const float*)d_in[1];
  const float* gb = (const float*)d_in[2];
  const float* w1 = (const float*)d_in[3];
  const float* b1 = (const float*)d_in[4];
  const float* w2 = (const float*)d_in[5];
  const float* b2 = (const float*)d_in[6];
  float* out = (float*)d_out;

  char* p = (char*)d_ws;
  _Float16* xh = (_Float16*)p;  p += (size_t)T_TOK * HID * 2;           // 11.8 MB
  _Float16* ab = (_Float16*)p;  p += (size_t)T_TOK * TOPK * INTERM * 2; // 47.2 MB
  float* cw    = (float*)p;     p += (size_t)T_TOK * NEXP * 4;
  int* list    = (int*)p;       p += (size_t)NEXP * T_TOK * 4;
  int* cnt     = (int*)p;       p += 256;
  int* offs    = (int*)p;       p += 256;

  hipMemsetAsync(cnt, 0, 512, stream);                       // cnt + offs
  hipMemsetAsync(d_out, 0, (size_t)out_size * 4, stream);    // atomic target

  k_cvt<<<dim3(T_TOK * HID / 4 / 256), dim3(256), 0, stream>>>(x, xh);
  k_router<<<dim3(T_TOK), dim3(64), 0, stream>>>(x, gw, gb, cw, list, cnt);
  k_scan<<<dim3(1), dim3(64), 0, stream>>>(cnt, offs);
  k_gemm1<<<dim3(INTERM / 64, T_TOK / 128, NEXP), dim3(256), 0, stream>>>(
      xh, w1, b1, list, cnt, offs, ab);
  k_gemm2<<<dim3(HID / 64, T_TOK / 128, NEXP), dim3(256), 0, stream>>>(
      ab, w2, b2, list, cnt, offs, cw, out);
}